// Round 3
// baseline (38.062 us; speedup 1.0000x reference)
//
#include <hip/hip_runtime.h>
#include <hip/hip_cooperative_groups.h>

namespace cg = cooperative_groups;

#define BATCH 1024
#define FEAT_DIM 512

// Single cooperative dispatch: 256 blocks x 256 threads (4 waves/block,
// 1 block/CU -> all co-resident, grid.sync() is valid).
// Phase 1: each wave owns one sample; lane loads 8 contiguous floats (two
//          float4) of x and of the gathered center row; shuffle-reduce;
//          block combines its 4 wave partials via LDS; plain store ws[blk].
// Phase 2: grid.sync(); block 0 wave 0 reduces the 256 block partials and
//          writes the mean with a single plain store. No atomics, no memset.
__global__ __launch_bounds__(256) void cl_coop(
    const float* __restrict__ x,
    const int* __restrict__ labels,
    const float* __restrict__ centers,
    float* __restrict__ ws,
    float* __restrict__ out)
{
    const int wave = threadIdx.x >> 6;
    const int lane = threadIdx.x & 63;
    const int b    = blockIdx.x * 4 + wave;

    const int label = labels[b];

    const float4* __restrict__ xr =
        reinterpret_cast<const float4*>(x + (size_t)b * FEAT_DIM);
    const float4* __restrict__ cr =
        reinterpret_cast<const float4*>(centers + (size_t)label * FEAT_DIM);

    const float4 a0 = xr[lane];
    const float4 a1 = xr[lane + 64];
    const float4 c0 = cr[lane];
    const float4 c1 = cr[lane + 64];

    const float d0 = a0.x - c0.x, d1 = a0.y - c0.y;
    const float d2 = a0.z - c0.z, d3 = a0.w - c0.w;
    const float d4 = a1.x - c1.x, d5 = a1.y - c1.y;
    const float d6 = a1.z - c1.z, d7 = a1.w - c1.w;

    float s = d0 * d0 + d1 * d1 + d2 * d2 + d3 * d3
            + d4 * d4 + d5 * d5 + d6 * d6 + d7 * d7;

    #pragma unroll
    for (int off = 32; off > 0; off >>= 1)
        s += __shfl_down(s, off, 64);

    __shared__ float wsum[4];
    if (lane == 0) wsum[wave] = s;
    __syncthreads();

    if (threadIdx.x == 0)
        ws[blockIdx.x] = wsum[0] + wsum[1] + wsum[2] + wsum[3];

    cg::this_grid().sync();

    if (blockIdx.x == 0 && threadIdx.x < 64) {
        const int l = threadIdx.x;
        float t = ws[l] + ws[l + 64] + ws[l + 128] + ws[l + 192];
        #pragma unroll
        for (int off = 32; off > 0; off >>= 1)
            t += __shfl_down(t, off, 64);
        if (l == 0) out[0] = t * (0.5f / (float)BATCH);
    }
}

extern "C" void kernel_launch(void* const* d_in, const int* in_sizes, int n_in,
                              void* d_out, int out_size, void* d_ws, size_t ws_size,
                              hipStream_t stream) {
    const float* x       = (const float*)d_in[0];
    const int*   labels  = (const int*)d_in[1];
    const float* centers = (const float*)d_in[2];
    float*       out     = (float*)d_out;
    float*       ws      = (float*)d_ws;

    void* args[] = {(void*)&x, (void*)&labels, (void*)&centers,
                    (void*)&ws, (void*)&out};
    hipLaunchCooperativeKernel((const void*)cl_coop, dim3(256), dim3(256),
                               args, 0, stream);
}

// Round 4
// 11.015 us; speedup vs baseline: 3.4554x; 3.4554x over previous
//
#include <hip/hip_runtime.h>

#define BATCH 1024
#define FEAT_DIM 512
#define NBLK 256
#define MAGIC 0x5CA1AB1Eu

// Single dispatch, no grid barrier. 256 blocks x 256 threads (4 waves).
// Each wave owns one sample (lane reads 8 contiguous floats = two float4
// of x and of the gathered center row), shuffle-reduces, block combines
// its 4 wave partials in LDS. Thread 0 publishes the block partial with
// an agent-scope atomic store + release flag. Block 0 wave 0 spin-polls
// all 256 flags (acquire, 4 per lane), reduces, writes out, resets flags
// to 0 so every graph replay starts from the same state (poison 0xAA !=
// MAGIC, so the first post-poison replay also waits correctly).
__global__ __launch_bounds__(256) void cl_fused(
    const float* __restrict__ x,
    const int* __restrict__ labels,
    const float* __restrict__ centers,
    float* __restrict__ partial,          // ws floats [0..255]
    unsigned int* __restrict__ flags,     // ws uints, separate 1KB region
    float* __restrict__ out)
{
    const int wave = threadIdx.x >> 6;
    const int lane = threadIdx.x & 63;
    const int b    = blockIdx.x * 4 + wave;

    const int label = labels[b];

    const float4* __restrict__ xr =
        reinterpret_cast<const float4*>(x + (size_t)b * FEAT_DIM);
    const float4* __restrict__ cr =
        reinterpret_cast<const float4*>(centers + (size_t)label * FEAT_DIM);

    const float4 a0 = xr[lane];
    const float4 a1 = xr[lane + 64];
    const float4 c0 = cr[lane];
    const float4 c1 = cr[lane + 64];

    const float d0 = a0.x - c0.x, d1 = a0.y - c0.y;
    const float d2 = a0.z - c0.z, d3 = a0.w - c0.w;
    const float d4 = a1.x - c1.x, d5 = a1.y - c1.y;
    const float d6 = a1.z - c1.z, d7 = a1.w - c1.w;

    float s = d0 * d0 + d1 * d1 + d2 * d2 + d3 * d3
            + d4 * d4 + d5 * d5 + d6 * d6 + d7 * d7;

    #pragma unroll
    for (int off = 32; off > 0; off >>= 1)
        s += __shfl_down(s, off, 64);

    __shared__ float wsum[4];
    if (lane == 0) wsum[wave] = s;
    __syncthreads();

    if (threadIdx.x == 0) {
        const float p = wsum[0] + wsum[1] + wsum[2] + wsum[3];
        // Publish partial + flag through the point of coherence (agent scope).
        __hip_atomic_store(&partial[blockIdx.x], p,
                           __ATOMIC_RELAXED, __HIP_MEMORY_SCOPE_AGENT);
        __hip_atomic_store(&flags[blockIdx.x], MAGIC,
                           __ATOMIC_RELEASE, __HIP_MEMORY_SCOPE_AGENT);
    }

    // Finisher: block 0, wave 0.
    if (blockIdx.x == 0 && wave == 0) {
        const int i0 = lane, i1 = lane + 64, i2 = lane + 128, i3 = lane + 192;
        bool done = false;
        while (!__all(done)) {
            done = (__hip_atomic_load(&flags[i0], __ATOMIC_ACQUIRE,
                                      __HIP_MEMORY_SCOPE_AGENT) == MAGIC)
                && (__hip_atomic_load(&flags[i1], __ATOMIC_ACQUIRE,
                                      __HIP_MEMORY_SCOPE_AGENT) == MAGIC)
                && (__hip_atomic_load(&flags[i2], __ATOMIC_ACQUIRE,
                                      __HIP_MEMORY_SCOPE_AGENT) == MAGIC)
                && (__hip_atomic_load(&flags[i3], __ATOMIC_ACQUIRE,
                                      __HIP_MEMORY_SCOPE_AGENT) == MAGIC);
            if (!done) __builtin_amdgcn_s_sleep(2);
        }

        float t = __hip_atomic_load(&partial[i0], __ATOMIC_RELAXED,
                                    __HIP_MEMORY_SCOPE_AGENT)
                + __hip_atomic_load(&partial[i1], __ATOMIC_RELAXED,
                                    __HIP_MEMORY_SCOPE_AGENT)
                + __hip_atomic_load(&partial[i2], __ATOMIC_RELAXED,
                                    __HIP_MEMORY_SCOPE_AGENT)
                + __hip_atomic_load(&partial[i3], __ATOMIC_RELAXED,
                                    __HIP_MEMORY_SCOPE_AGENT);

        #pragma unroll
        for (int off = 32; off > 0; off >>= 1)
            t += __shfl_down(t, off, 64);

        if (lane == 0) out[0] = t * (0.5f / (float)BATCH);

        // Reset flags so every replay starts identically (deterministic).
        __hip_atomic_store(&flags[i0], 0u, __ATOMIC_RELAXED, __HIP_MEMORY_SCOPE_AGENT);
        __hip_atomic_store(&flags[i1], 0u, __ATOMIC_RELAXED, __HIP_MEMORY_SCOPE_AGENT);
        __hip_atomic_store(&flags[i2], 0u, __ATOMIC_RELAXED, __HIP_MEMORY_SCOPE_AGENT);
        __hip_atomic_store(&flags[i3], 0u, __ATOMIC_RELAXED, __HIP_MEMORY_SCOPE_AGENT);
    }
}

extern "C" void kernel_launch(void* const* d_in, const int* in_sizes, int n_in,
                              void* d_out, int out_size, void* d_ws, size_t ws_size,
                              hipStream_t stream) {
    const float* x       = (const float*)d_in[0];
    const int*   labels  = (const int*)d_in[1];
    const float* centers = (const float*)d_in[2];
    float*       out     = (float*)d_out;

    float*        partial = (float*)d_ws;                      // 256 floats = 1 KB
    unsigned int* flags   = (unsigned int*)((char*)d_ws + 1024); // 256 uints = 1 KB

    cl_fused<<<NBLK, 256, 0, stream>>>(x, labels, centers, partial, flags, out);
}

// Round 5
// 9.529 us; speedup vs baseline: 3.9945x; 1.1560x over previous
//
#include <hip/hip_runtime.h>

#define BATCH 1024
#define FEAT_DIM 512
#define NBLK 128           // 128 blocks x 4 waves x 2 samples = 1024 samples
#define MAGIC 0x5CA1AB1Eu

// Single dispatch, flag-based completion (poison-safe: 0xAA pattern != MAGIC,
// and the finisher resets flags to 0 so every replay starts identically).
// Each 64-lane wave owns 2 samples; per lane: 8 independent 16B loads in
// flight (4 of x, 4 of gathered centers). Labels are loaded first so the
// x-loads overlap the label->center dependent chain.
__global__ __launch_bounds__(256) void cl_fused(
    const float* __restrict__ x,
    const int* __restrict__ labels,
    const float* __restrict__ centers,
    float* __restrict__ partial,          // 128 floats
    unsigned int* __restrict__ flags,     // 128 uints (separate 1KB region)
    float* __restrict__ out)
{
    const int wave = threadIdx.x >> 6;
    const int lane = threadIdx.x & 63;
    const int b0   = blockIdx.x * 8 + wave * 2;
    const int b1   = b0 + 1;

    // Issue label loads first (they gate the center-row addresses).
    const int lab0 = labels[b0];
    const int lab1 = labels[b1];

    const float4* __restrict__ x0 =
        reinterpret_cast<const float4*>(x + (size_t)b0 * FEAT_DIM);
    const float4* __restrict__ x1 =
        reinterpret_cast<const float4*>(x + (size_t)b1 * FEAT_DIM);
    const float4* __restrict__ c0 =
        reinterpret_cast<const float4*>(centers + (size_t)lab0 * FEAT_DIM);
    const float4* __restrict__ c1 =
        reinterpret_cast<const float4*>(centers + (size_t)lab1 * FEAT_DIM);

    const float4 xa = x0[lane];
    const float4 xb = x0[lane + 64];
    const float4 xc = x1[lane];
    const float4 xd = x1[lane + 64];
    const float4 ca = c0[lane];
    const float4 cb = c0[lane + 64];
    const float4 cc = c1[lane];
    const float4 cd = c1[lane + 64];

    float s;
    {
        const float e0 = xa.x - ca.x, e1 = xa.y - ca.y;
        const float e2 = xa.z - ca.z, e3 = xa.w - ca.w;
        const float e4 = xb.x - cb.x, e5 = xb.y - cb.y;
        const float e6 = xb.z - cb.z, e7 = xb.w - cb.w;
        const float f0 = xc.x - cc.x, f1 = xc.y - cc.y;
        const float f2 = xc.z - cc.z, f3 = xc.w - cc.w;
        const float f4 = xd.x - cd.x, f5 = xd.y - cd.y;
        const float f6 = xd.z - cd.z, f7 = xd.w - cd.w;
        s = e0 * e0 + e1 * e1 + e2 * e2 + e3 * e3
          + e4 * e4 + e5 * e5 + e6 * e6 + e7 * e7
          + f0 * f0 + f1 * f1 + f2 * f2 + f3 * f3
          + f4 * f4 + f5 * f5 + f6 * f6 + f7 * f7;
    }

    #pragma unroll
    for (int off = 32; off > 0; off >>= 1)
        s += __shfl_down(s, off, 64);

    __shared__ float wsum[4];
    if (lane == 0) wsum[wave] = s;
    __syncthreads();

    if (threadIdx.x == 0) {
        const float p = wsum[0] + wsum[1] + wsum[2] + wsum[3];
        __hip_atomic_store(&partial[blockIdx.x], p,
                           __ATOMIC_RELAXED, __HIP_MEMORY_SCOPE_AGENT);
        __hip_atomic_store(&flags[blockIdx.x], MAGIC,
                           __ATOMIC_RELEASE, __HIP_MEMORY_SCOPE_AGENT);
    }

    // Finisher: block 0, wave 0 polls the 128 flags (2 per lane).
    if (blockIdx.x == 0 && wave == 0) {
        const int i0 = lane, i1 = lane + 64;
        bool done = false;
        while (!__all(done)) {
            done = (__hip_atomic_load(&flags[i0], __ATOMIC_ACQUIRE,
                                      __HIP_MEMORY_SCOPE_AGENT) == MAGIC)
                && (__hip_atomic_load(&flags[i1], __ATOMIC_ACQUIRE,
                                      __HIP_MEMORY_SCOPE_AGENT) == MAGIC);
            if (!done) __builtin_amdgcn_s_sleep(2);
        }

        float t = __hip_atomic_load(&partial[i0], __ATOMIC_RELAXED,
                                    __HIP_MEMORY_SCOPE_AGENT)
                + __hip_atomic_load(&partial[i1], __ATOMIC_RELAXED,
                                    __HIP_MEMORY_SCOPE_AGENT);

        #pragma unroll
        for (int off = 32; off > 0; off >>= 1)
            t += __shfl_down(t, off, 64);

        if (lane == 0) out[0] = t * (0.5f / (float)BATCH);

        __hip_atomic_store(&flags[i0], 0u, __ATOMIC_RELAXED, __HIP_MEMORY_SCOPE_AGENT);
        __hip_atomic_store(&flags[i1], 0u, __ATOMIC_RELAXED, __HIP_MEMORY_SCOPE_AGENT);
    }
}

extern "C" void kernel_launch(void* const* d_in, const int* in_sizes, int n_in,
                              void* d_out, int out_size, void* d_ws, size_t ws_size,
                              hipStream_t stream) {
    const float* x       = (const float*)d_in[0];
    const int*   labels  = (const int*)d_in[1];
    const float* centers = (const float*)d_in[2];
    float*       out     = (float*)d_out;

    float*        partial = (float*)d_ws;                        // 128 floats
    unsigned int* flags   = (unsigned int*)((char*)d_ws + 1024); // 128 uints

    cl_fused<<<NBLK, 256, 0, stream>>>(x, labels, centers, partial, flags, out);
}